// Round 10
// baseline (24.714 us; speedup 1.0000x reference)
//
#include <hip/hip_runtime.h>

#define B 16
#define T 2048
#define D 1024
#define Q 64                 // t-chunks per batch
#define NP (B * Q)           // 1024 partial rows in ws

#define FMA4(c, v, a)                    \
    do {                                 \
        (a).x = fmaf((c), (v).x, (a).x); \
        (a).y = fmaf((c), (v).y, (a).y); \
        (a).z = fmaf((c), (v).z, (a).z); \
        (a).w = fmaf((c), (v).w, (a).w); \
    } while (0)

// K1: CONTIGUOUS full-row streaming (tests the per-CU scattered-128B-cap
// theory that explains R6/R8/R9's identical 18.2us: each old wave-load
// touched 8 x 128B segments at 4KB stride -> outstanding-line-limited
// ~20 GB/s/CU; here every wave-load is 1KB contiguous).
// Block (b, q): rows [q*nq, min((q+1)*nq, len)), nq = ceil(len/Q) <= 32
// (longest block 128KB -> tail term gone). 256 thr x float4 = 4KB/row.
// Accumulates an UNNORMALIZED full-row partial (coeff = exp(w[t]);
// weights~N(0,1) so no overflow; 1/sum applied in K2), plain-stores 4KB
// to ws. All NP partials written unconditionally (ws is poisoned).
__global__ __launch_bounds__(256) void stream_kernel(
    const float* __restrict__ input,
    const int* __restrict__ lengths,
    const float* __restrict__ weights,
    float* __restrict__ ws) {
    const int b   = blockIdx.x & (B - 1);   // batch varies fastest
    const int q   = blockIdx.x >> 4;
    const int tid = threadIdx.x;
    const int len = lengths[b];
    const int nq  = (len + Q - 1) >> 6;     // ceil(len/64) rows per chunk
    const int t0  = q * nq;
    const int t1  = min(t0 + nq, len);

    const float4* __restrict__ in4 =
        (const float4*)input + (size_t)b * T * (D / 4) + tid;

    float4 acc = make_float4(0.f, 0.f, 0.f, 0.f);
#pragma unroll 4
    for (int t = t0; t < t1; ++t) {
        const float  c = expf(weights[t]);            // uniform scalar
        const float4 v = in4[(size_t)t * (D / 4)];    // 1KB contiguous/wave
        FMA4(c, v, acc);
    }
    ((float4*)ws)[(size_t)blockIdx.x * (D / 4) + tid] = acc;
}

// K2: combine. 64 blocks (b x 4 d-slices); per-block softmax denominator
// (2048 expf, trivial); each thread sums its output element over the 64
// q-partials (per q-iteration the block reads 1KB contiguous, L2/L3-hot,
// 4MB total), scales by 1/sum, overwrites out fully (no zero-init needed).
__global__ __launch_bounds__(256) void combine_kernel(
    const float* __restrict__ weights,
    const float* __restrict__ ws,
    float* __restrict__ out) {
    const int tid = threadIdx.x;
    const int b   = blockIdx.x >> 2;
    const int ds  = blockIdx.x & 3;
    const int d   = ds * 256 + tid;

    // softmax denominator
    float lsum = 0.f;
#pragma unroll
    for (int i = 0; i < 8; ++i)
        lsum += expf(weights[tid * 8 + i]);
#pragma unroll
    for (int off = 32; off > 0; off >>= 1)
        lsum += __shfl_xor(lsum, off);
    __shared__ float red[4];
    if ((tid & 63) == 0) red[tid >> 6] = lsum;
    __syncthreads();
    const float inv = 1.f / (red[0] + red[1] + red[2] + red[3]);

    // partial (b,q) lives at ws[(q*16 + b)*D]; fixed b -> stride 16*D
    const float* __restrict__ p = ws + (size_t)b * D + d;
    float s = 0.f;
#pragma unroll 8
    for (int q = 0; q < Q; ++q)
        s += p[(size_t)q * (B * D)];

    out[b * D + d] = s * inv;
}

extern "C" void kernel_launch(void* const* d_in, const int* in_sizes, int n_in,
                              void* d_out, int out_size, void* d_ws, size_t ws_size,
                              hipStream_t stream) {
    const float* input   = (const float*)d_in[0];
    const int*   lengths = (const int*)d_in[1];
    const float* weights = (const float*)d_in[2];
    float* out = (float*)d_out;
    float* ws  = (float*)d_ws;   // NP x 4KB = 4 MB scratch

    stream_kernel<<<NP, 256, 0, stream>>>(input, lengths, weights, ws);
    combine_kernel<<<B * 4, 256, 0, stream>>>(weights, ws, out);
}

// Round 11
// 21.889 us; speedup vs baseline: 1.1291x; 1.1291x over previous
//
#include <hip/hip_runtime.h>

#define B 16
#define T 2048
#define D 1024
#define NSLICE 32            // slice-blocks per batch
#define SLICE (D / NSLICE)   // 32 floats = 8 float4 per block

typedef float f32x4 __attribute__((ext_vector_type(4)));

// R6 structure verbatim (single kernel, slice-columns, single-writer
// stores, no atomics/fences/scratch/memset) with ONE change: the input
// stream uses NONTEMPORAL loads. Each 128B input line is read exactly
// once per replay by exactly one block (slices partition lines), so L1/L2
// allocation is pure overhead; nt marks the stream no-allocate. A/B vs
// R6's 18.24us isolates the cache-path cost. If null, the ~4.4 TB/s
// read-stream ceiling (vs 7.2 TB/s measured pure-write) is structural.
__global__ __launch_bounds__(256, 4) void fused_nt_kernel(
    const float* __restrict__ input,
    const int* __restrict__ lengths,
    const float* __restrict__ weights,
    float* __restrict__ out) {
    const int b   = blockIdx.x >> 5;   // batch
    const int s   = blockIdx.x & 31;   // slice
    const int tid = threadIdx.x;
    const int c   = tid & 7;           // float4 column within slice
    const int rp  = tid >> 3;          // row phase 0..31
    const int len = lengths[b];

    const f32x4* __restrict__ in4 =
        (const f32x4*)input + (size_t)b * T * (D / 4) + s * (SLICE / 4) + c;

    float ax = 0.f, ay = 0.f, az = 0.f, aw = 0.f;

    // full 32-row groups: rows it*32+rp all < len
    const int nfull = len >> 5;
    const float*  wr = weights + rp;
    const f32x4*  p  = in4 + (size_t)rp * (D / 4);
#pragma unroll 4
    for (int it = 0; it < nfull; ++it) {
        const float cw = expf(wr[it * 32]);
        const f32x4 v  = __builtin_nontemporal_load(&p[(size_t)it * 32 * (D / 4)]);
        ax = fmaf(cw, v.x, ax);
        ay = fmaf(cw, v.y, ay);
        az = fmaf(cw, v.z, az);
        aw = fmaf(cw, v.w, aw);
    }
    // tail group: mask rows >= len (coeff 0, row not loaded)
    const int r = nfull * 32 + rp;
    if (r < len) {
        const float cw = expf(weights[r]);
        const f32x4 v  = __builtin_nontemporal_load(&in4[(size_t)r * (D / 4)]);
        ax = fmaf(cw, v.x, ax);
        ay = fmaf(cw, v.y, ay);
        az = fmaf(cw, v.z, az);
        aw = fmaf(cw, v.w, aw);
    }

    // softmax denominator (redundant per block; 8 expf/thread, once)
    float lsum = 0.f;
#pragma unroll
    for (int i = 0; i < 8; ++i)
        lsum += expf(weights[tid * 8 + i]);
#pragma unroll
    for (int off = 32; off > 0; off >>= 1)
        lsum += __shfl_xor(lsum, off);
    __shared__ float red[4];
    if ((tid & 63) == 0) red[tid >> 6] = lsum;
    __syncthreads();
    const float inv = 1.f / (red[0] + red[1] + red[2] + red[3]);

    // LDS tree-reduce over the 32 row-phases
    __shared__ float4 lds[32][8];
    lds[rp][c] = make_float4(ax, ay, az, aw);
    __syncthreads();
    float4 acc = lds[rp][c];
#pragma unroll
    for (int off = 16; off > 0; off >>= 1) {
        if (rp < off) {
            const float4 o = lds[rp + off][c];
            acc.x += o.x; acc.y += o.y; acc.z += o.z; acc.w += o.w;
            lds[rp][c] = acc;
        }
        __syncthreads();
    }

    if (tid < 8) {   // rp==0, c==tid: single writer
        const float4 r4 = make_float4(acc.x * inv, acc.y * inv,
                                      acc.z * inv, acc.w * inv);
        ((float4*)out)[b * (D / 4) + s * (SLICE / 4) + tid] = r4;
    }
}

extern "C" void kernel_launch(void* const* d_in, const int* in_sizes, int n_in,
                              void* d_out, int out_size, void* d_ws, size_t ws_size,
                              hipStream_t stream) {
    const float* input   = (const float*)d_in[0];
    const int*   lengths = (const int*)d_in[1];
    const float* weights = (const float*)d_in[2];
    float* out = (float*)d_out;

    fused_nt_kernel<<<B * NSLICE, 256, 0, stream>>>(input, lengths, weights, out);
}